// Round 1
// baseline (599.726 us; speedup 1.0000x reference)
//
#include <hip/hip_runtime.h>
#include <hip/hip_bf16.h>
#include <cstdint>
#include <cstddef>

#define B_   32
#define S_   2048
#define DH_  1024
#define DF_  1024
#define DM_  512
#define MTOT (B_ * S_)   // 65536

typedef __attribute__((ext_vector_type(8))) short bf16x8;
typedef __attribute__((ext_vector_type(4))) float f32x4;

// round-to-nearest-even fp32 -> bf16, packed pair
static __device__ __forceinline__ unsigned pack_bf16_2(float a, float b) {
    unsigned ua = __float_as_uint(a);
    unsigned ub = __float_as_uint(b);
    ua = (ua + 0x7FFFu + ((ua >> 16) & 1u)) >> 16;
    ub = (ub + 0x7FFFu + ((ub >> 16) & 1u)) >> 16;
    return ua | (ub << 16);
}

// tanh(x) = 1 - 2/(e^{2x}+1); saturates correctly at +-inf of exp
static __device__ __forceinline__ float tanh_fast(float x) {
    float e = __expf(2.0f * x);
    return 1.0f - 2.0f / (e + 1.0f);
}

// ---------------------------------------------------------------------------
// Kernel 1a: embh[b][m] = dot(hidden[b], W1h[m]) + b1h[m] + b1f[m]
// ---------------------------------------------------------------------------
__global__ __launch_bounds__(256) void k_embh(
    const float* __restrict__ hidden, const float* __restrict__ W1h,
    const float* __restrict__ b1h, const float* __restrict__ b1f,
    float* __restrict__ embh)
{
    int b = blockIdx.x;
    int t = threadIdx.x;
    const float4* h4 = (const float4*)(hidden + (size_t)b * DH_);
    for (int m = t; m < DM_; m += 256) {
        const float4* w4 = (const float4*)(W1h + (size_t)m * DH_);
        float s = 0.0f;
        #pragma unroll 4
        for (int i = 0; i < DH_ / 4; ++i) {
            float4 a = h4[i];
            float4 w = w4[i];
            s += a.x * w.x + a.y * w.y + a.z * w.z + a.w * w.w;
        }
        embh[b * DM_ + m] = s + b1h[m] + b1f[m];
    }
}

// ---------------------------------------------------------------------------
// Kernel 1b: convert W1f (fp32, [DM][DF]) -> bf16
// ---------------------------------------------------------------------------
__global__ __launch_bounds__(256) void k_cvt_w1f(
    const float* __restrict__ w1f, unsigned short* __restrict__ out)
{
    int i = blockIdx.x * 256 + threadIdx.x;   // group of 4 elements
    float4 v = ((const float4*)w1f)[i];
    uint2 o;
    o.x = pack_bf16_2(v.x, v.y);
    o.y = pack_bf16_2(v.z, v.w);
    ((uint2*)out)[i] = o;
}

// ---------------------------------------------------------------------------
// Kernel 2: big GEMM (feats @ W1f^T) + fused tanh/w2 epilogue -> partial logits
//   Tile 128(M) x 128(N) x 32(K); 4 waves, each 64x64 via 4x4 mfma 16x16x32.
//   LDS layout: chunk-of-8 [kchunk][row], 16B entries -> aligned b128 ops.
//   plog layout: [8 = blockIdx.x*2 + wn][B][S]
// ---------------------------------------------------------------------------
__global__ __launch_bounds__(256) void k_gemm_logits(
    const float* __restrict__ feats, const unsigned short* __restrict__ w1fb,
    const float* __restrict__ embh, const float* __restrict__ w2,
    float* __restrict__ plog)
{
    __shared__ bf16x8 As[4 * 128];   // 8 KB
    __shared__ bf16x8 Bs[4 * 128];   // 8 KB

    const int t    = threadIdx.x;
    const int lane = t & 63;
    const int w    = t >> 6;
    const int wm   = w >> 1;
    const int wn   = w & 1;
    const int quad = lane >> 4;
    const int l16  = lane & 15;
    const int bx   = blockIdx.x;   // N tile (0..3)
    const int by   = blockIdx.y;   // M tile (0..511)

    // staging assignment: thread covers row sRow, k in [sK, sK+16)
    const int sRow = t >> 1;
    const int sK   = (t & 1) * 16;
    const int c0   = sK >> 3;   // first chunk index (0 or 2)
    const float*          aG = feats + (size_t)(by * 128 + sRow) * DF_ + sK;
    const unsigned short* bG = w1fb  + (size_t)(bx * 128 + sRow) * DF_ + sK;

    f32x4 acc[4][4];
    const f32x4 zero = {0.0f, 0.0f, 0.0f, 0.0f};
    #pragma unroll
    for (int i = 0; i < 4; ++i)
        #pragma unroll
        for (int j = 0; j < 4; ++j) acc[i][j] = zero;

    for (int kt = 0; kt < DF_ / 32; ++kt) {
        // global loads (fp32 A, bf16 B)
        float4 a0 = *(const float4*)(aG + kt * 32);
        float4 a1 = *(const float4*)(aG + kt * 32 + 4);
        float4 a2 = *(const float4*)(aG + kt * 32 + 8);
        float4 a3 = *(const float4*)(aG + kt * 32 + 12);
        uint4  b0 = *(const uint4*)(bG + kt * 32);
        uint4  b1 = *(const uint4*)(bG + kt * 32 + 8);

        __syncthreads();   // previous iter's reads done

        union { unsigned u[4]; bf16x8 v; } pa;
        pa.u[0] = pack_bf16_2(a0.x, a0.y);
        pa.u[1] = pack_bf16_2(a0.z, a0.w);
        pa.u[2] = pack_bf16_2(a1.x, a1.y);
        pa.u[3] = pack_bf16_2(a1.z, a1.w);
        As[c0 * 128 + sRow] = pa.v;
        pa.u[0] = pack_bf16_2(a2.x, a2.y);
        pa.u[1] = pack_bf16_2(a2.z, a2.w);
        pa.u[2] = pack_bf16_2(a3.x, a3.y);
        pa.u[3] = pack_bf16_2(a3.z, a3.w);
        As[(c0 + 1) * 128 + sRow] = pa.v;

        union { uint4 q; bf16x8 v; } pb;
        pb.q = b0;
        Bs[c0 * 128 + sRow] = pb.v;
        pb.q = b1;
        Bs[(c0 + 1) * 128 + sRow] = pb.v;

        __syncthreads();   // tiles ready

        bf16x8 af[4], bfr[4];
        #pragma unroll
        for (int mi = 0; mi < 4; ++mi)
            af[mi] = As[quad * 128 + wm * 64 + mi * 16 + l16];
        #pragma unroll
        for (int nj = 0; nj < 4; ++nj)
            bfr[nj] = Bs[quad * 128 + wn * 64 + nj * 16 + l16];

        #pragma unroll
        for (int mi = 0; mi < 4; ++mi)
            #pragma unroll
            for (int nj = 0; nj < 4; ++nj)
                acc[mi][nj] = __builtin_amdgcn_mfma_f32_16x16x32_bf16(
                    af[mi], bfr[nj], acc[mi][nj], 0, 0, 0);
    }

    // Epilogue: logit partial = sum over this block's 128 columns of
    //   tanh(acc + embh[b][col]) * w2[col]
    const int bIdx = by >> 4;   // 16 M-tiles per batch row (2048/128)
    float ew[4], wv[4];
    #pragma unroll
    for (int nj = 0; nj < 4; ++nj) {
        int c = bx * 128 + wn * 64 + nj * 16 + l16;
        ew[nj] = embh[bIdx * DM_ + c];
        wv[nj] = w2[c];
    }
    float* plw = plog + (size_t)(bx * 2 + wn) * MTOT + bIdx * S_;
    #pragma unroll
    for (int mi = 0; mi < 4; ++mi) {
        #pragma unroll
        for (int reg = 0; reg < 4; ++reg) {
            float p = 0.0f;
            #pragma unroll
            for (int nj = 0; nj < 4; ++nj) {
                float v = acc[mi][nj][reg] + ew[nj];
                p += tanh_fast(v) * wv[nj];
            }
            // reduce across the 16 lanes holding different columns
            p += __shfl_xor(p, 1);
            p += __shfl_xor(p, 2);
            p += __shfl_xor(p, 4);
            p += __shfl_xor(p, 8);
            if (l16 == 0) {
                int rowl = wm * 64 + mi * 16 + quad * 4 + reg;
                int s = (by * 128 + rowl) & (S_ - 1);
                plw[s] = p;
            }
        }
    }
}

// ---------------------------------------------------------------------------
// Kernel 3: combine 8 partials, softmax over S per batch row
// ---------------------------------------------------------------------------
__global__ __launch_bounds__(256) void k_softmax(
    const float* __restrict__ plog, float* __restrict__ probs_out)
{
    int b = blockIdx.x;
    int t = threadIdx.x;
    float l[8];
    #pragma unroll
    for (int i = 0; i < 8; ++i) {
        int s = t + i * 256;
        float sum = 0.0f;
        #pragma unroll
        for (int p = 0; p < 8; ++p)
            sum += plog[(size_t)p * MTOT + b * S_ + s];
        l[i] = sum;
    }
    float mx = l[0];
    #pragma unroll
    for (int i = 1; i < 8; ++i) mx = fmaxf(mx, l[i]);
    #pragma unroll
    for (int off = 1; off < 64; off <<= 1) mx = fmaxf(mx, __shfl_xor(mx, off));
    __shared__ float redm[4];
    __shared__ float reds[4];
    int wid = t >> 6;
    if ((t & 63) == 0) redm[wid] = mx;
    __syncthreads();
    mx = fmaxf(fmaxf(redm[0], redm[1]), fmaxf(redm[2], redm[3]));

    float e[8];
    float es = 0.0f;
    #pragma unroll
    for (int i = 0; i < 8; ++i) {
        e[i] = __expf(l[i] - mx);
        es += e[i];
    }
    #pragma unroll
    for (int off = 1; off < 64; off <<= 1) es += __shfl_xor(es, off);
    if ((t & 63) == 0) reds[wid] = es;
    __syncthreads();
    es = reds[0] + reds[1] + reds[2] + reds[3];
    float inv = 1.0f / es;
    #pragma unroll
    for (int i = 0; i < 8; ++i)
        probs_out[b * S_ + t + i * 256] = e[i] * inv;
}

// ---------------------------------------------------------------------------
// Kernel 4: context[b][d] = sum_s probs[b][s] * feats[b][s][d]
//   grid (DF/256, B, 8 s-chunks); atomic accumulate into zeroed d_out
// ---------------------------------------------------------------------------
__global__ __launch_bounds__(256) void k_context(
    const float* __restrict__ feats, const float* __restrict__ probs,
    float* __restrict__ ctx)
{
    int d  = blockIdx.x * 256 + threadIdx.x;
    int b  = blockIdx.y;
    int s0 = blockIdx.z * 256;
    const float* f  = feats + ((size_t)b * S_ + s0) * DF_ + d;
    const float* pr = probs + b * S_ + s0;
    float acc = 0.0f;
    #pragma unroll 4
    for (int i = 0; i < 256; ++i)
        acc += pr[i] * f[(size_t)i * DF_];
    atomicAdd(&ctx[b * DF_ + d], acc);
}

// ---------------------------------------------------------------------------
extern "C" void kernel_launch(void* const* d_in, const int* in_sizes, int n_in,
                              void* d_out, int out_size, void* d_ws, size_t ws_size,
                              hipStream_t stream)
{
    const float* hidden = (const float*)d_in[0];
    const float* feats  = (const float*)d_in[1];
    const float* W1h    = (const float*)d_in[2];
    const float* b1h    = (const float*)d_in[3];
    const float* W1f    = (const float*)d_in[4];
    const float* b1f    = (const float*)d_in[5];
    const float* w2     = (const float*)d_in[6];

    float* out   = (float*)d_out;
    float* ctx   = out;              // [B, DF]  (output 0)
    float* probs = out + B_ * DF_;   // [B, 1, S] (output 1)

    char* ws = (char*)d_ws;
    float*          embh = (float*)ws;                              // 64 KB
    unsigned short* w1fb = (unsigned short*)(ws + (64 << 10));      // 1 MB
    float*          plog = (float*)(ws + (64 << 10) + (1 << 20));   // 2 MB

    // context accumulated via atomics -> zero it (ws/d_out are poisoned)
    hipMemsetAsync(ctx, 0, B_ * DF_ * sizeof(float), stream);

    k_embh<<<dim3(B_), 256, 0, stream>>>(hidden, W1h, b1h, b1f, embh);
    k_cvt_w1f<<<dim3((DM_ * DF_ / 4) / 256), 256, 0, stream>>>(W1f, w1fb);
    k_gemm_logits<<<dim3(DM_ / 128, MTOT / 128), 256, 0, stream>>>(
        feats, w1fb, embh, w2, plog);
    k_softmax<<<dim3(B_), 256, 0, stream>>>(plog, probs);
    k_context<<<dim3(DF_ / 256, B_, 8), 256, 0, stream>>>(feats, probs, ctx);
}

// Round 2
// 587.936 us; speedup vs baseline: 1.0201x; 1.0201x over previous
//
#include <hip/hip_runtime.h>
#include <hip/hip_bf16.h>
#include <cstdint>
#include <cstddef>

#define B_   32
#define S_   2048
#define DH_  1024
#define DF_  1024
#define DM_  512
#define MTOT (B_ * S_)   // 65536

typedef __attribute__((ext_vector_type(8)))  short bf16x8;
typedef __attribute__((ext_vector_type(16))) float f32x16;

#define AS1 __attribute__((address_space(1)))
#define AS3 __attribute__((address_space(3)))

static __device__ __forceinline__ void load_lds16(const void* g, void* l) {
    __builtin_amdgcn_global_load_lds((const AS1 unsigned*)g, (AS3 unsigned*)l,
                                     16, 0, 0);
}

// fp32 pair -> packed bf16, round-half-up (cheap: ~4 VALU)
static __device__ __forceinline__ unsigned pack_rhu(float a, float b) {
    unsigned ua = (__float_as_uint(a) + 0x8000u) >> 16;
    unsigned ub = (__float_as_uint(b) + 0x8000u) & 0xFFFF0000u;
    return ua | ub;
}

static __device__ __forceinline__ float tanh_fast(float x) {
    float e = __expf(2.0f * x);
    return 1.0f - 2.0f / (e + 1.0f);
}

// ---------------------------------------------------------------------------
// Kernel 1a: embh[b][m] = dot(hidden[b], W1h[m]) + b1h[m] + b1f[m]
//   grid (B, DM/64); 4 threads per m (k split in quarters), shfl-reduce.
// ---------------------------------------------------------------------------
__global__ __launch_bounds__(256) void k_embh(
    const float* __restrict__ hidden, const float* __restrict__ W1h,
    const float* __restrict__ b1h, const float* __restrict__ b1f,
    float* __restrict__ embh)
{
    int b  = blockIdx.x;
    int mg = blockIdx.y;
    int t  = threadIdx.x;
    int m  = mg * 64 + (t >> 2);
    int kp = (t & 3) * 256;
    const float4* h4 = (const float4*)(hidden + (size_t)b * DH_ + kp);
    const float4* w4 = (const float4*)(W1h + (size_t)m * DH_ + kp);
    float s = 0.0f;
    #pragma unroll 8
    for (int i = 0; i < 64; ++i) {
        float4 a = h4[i];
        float4 w = w4[i];
        s += a.x * w.x + a.y * w.y + a.z * w.z + a.w * w.w;
    }
    s += __shfl_xor(s, 1);
    s += __shfl_xor(s, 2);
    if ((t & 3) == 0)
        embh[b * DM_ + m] = s + b1h[m] + b1f[m];
}

// ---------------------------------------------------------------------------
// Kernel 1b: convert W1f (fp32, [DM][DF]) -> bf16
// ---------------------------------------------------------------------------
__global__ __launch_bounds__(256) void k_cvt_w1f(
    const float* __restrict__ w1f, unsigned short* __restrict__ out)
{
    int i = blockIdx.x * 256 + threadIdx.x;   // group of 4 elements
    float4 v = ((const float4*)w1f)[i];
    uint2 o;
    o.x = pack_rhu(v.x, v.y);
    o.y = pack_rhu(v.z, v.w);
    ((uint2*)out)[i] = o;
}

// ---------------------------------------------------------------------------
// Kernel 2: feats @ W1f^T GEMM + fused tanh/w2 epilogue -> partial logits
//   Block tile 256(M) x 128(N), BK=32, mfma_f32_32x32x16_bf16.
//   4 waves as 2x2: wave tile 128(M) x 64(N) = 4x2 mfma tiles, 128 acc VGPR.
//   LDS: chunk-of-8 [c][row] 16B slots, double-buffered, ONE barrier/iter.
//   A: fp32 loads prefetched 1 iter ahead in regs, cheap cvt, b128 stores.
//   B: async global_load_lds (bf16 direct), issued just after the barrier.
//   Grid: 1D 1024, swizzled so the 4 bx-sharers of an A-tile are == mod 8
//   (same XCD -> A-tile served from one L2) and within a 32-block window.
//   plog streams: [bx*2 + wn][B][S]
// ---------------------------------------------------------------------------
__global__ __launch_bounds__(256, 2) void k_gemm_logits(
    const float* __restrict__ feats, const unsigned short* __restrict__ w1fb,
    const float* __restrict__ embh, const float* __restrict__ w2,
    float* __restrict__ plog)
{
    __shared__ bf16x8 As[2][4 * 256];   // 2 x 16 KB
    __shared__ bf16x8 Bs[2][4 * 128];   // 2 x  8 KB

    const int t    = threadIdx.x;
    const int lane = t & 63;
    const int w    = t >> 6;
    const int wm   = w >> 1;
    const int wn   = w & 1;
    const int l32  = lane & 31;
    const int half = lane >> 5;

    // swizzled grid decode
    const int blk   = blockIdx.x;
    const int panel = blk >> 5;
    const int sub   = blk & 31;
    const int bx    = sub >> 3;            // 0..3  (N tile)
    const int by    = panel * 8 + (sub & 7);   // 0..255 (M tile, 256 rows)

    // A: this thread owns row (by*256 + t), 32 k per iter (8 float4)
    const float* aG = feats + (size_t)(by * 256 + t) * DF_;

    // B: two async lds-direct ops per wave; slot s = (w*2+j)*64 + lane
    const int s0 = (w * 2 + 0) * 64 + lane;
    const int s1 = s0 + 64;
    const unsigned short* bG0 =
        w1fb + (size_t)(bx * 128 + (s0 & 127)) * DF_ + (s0 >> 7) * 8;
    const unsigned short* bG1 =
        w1fb + (size_t)(bx * 128 + (s1 & 127)) * DF_ + (s1 >> 7) * 8;
    const int ldsSlot0 = (w * 2 + 0) * 64;
    const int ldsSlot1 = (w * 2 + 1) * 64;

    f32x16 acc[4][2];
    #pragma unroll
    for (int mi = 0; mi < 4; ++mi)
        #pragma unroll
        for (int nj = 0; nj < 2; ++nj)
            #pragma unroll
            for (int r = 0; r < 16; ++r) acc[mi][nj][r] = 0.0f;

    // ---- prologue: A regs for kt=0, B lds-direct for kt=0 into buf 0
    float4 ar[8];
    #pragma unroll
    for (int j = 0; j < 8; ++j) ar[j] = ((const float4*)aG)[j];
    load_lds16(bG0, &Bs[0][ldsSlot0]);
    load_lds16(bG1, &Bs[0][ldsSlot1]);

    for (int kt = 0; kt < DF_ / 32; ++kt) {
        const int cur = kt & 1;
        const int nxt = cur ^ 1;

        // pack prefetched A into LDS buf[cur] (4 x b128, lane-contiguous)
        #pragma unroll
        for (int c = 0; c < 4; ++c) {
            union { unsigned u[4]; bf16x8 v; } pa;
            pa.u[0] = pack_rhu(ar[2 * c].x,     ar[2 * c].y);
            pa.u[1] = pack_rhu(ar[2 * c].z,     ar[2 * c].w);
            pa.u[2] = pack_rhu(ar[2 * c + 1].x, ar[2 * c + 1].y);
            pa.u[3] = pack_rhu(ar[2 * c + 1].z, ar[2 * c + 1].w);
            As[cur][c * 256 + t] = pa.v;
        }

        // prefetch A regs for kt+1 (consumed after next barrier)
        if (kt + 1 < DF_ / 32) {
            const float4* an = (const float4*)(aG + (kt + 1) * 32);
            #pragma unroll
            for (int j = 0; j < 8; ++j) ar[j] = an[j];
        }

        __syncthreads();   // drains vmcnt (B[cur] complete) + As[cur] visible

        // async B for kt+1 into buf[nxt] (safe: prev readers of nxt are done)
        if (kt + 1 < DF_ / 32) {
            load_lds16(bG0 + (kt + 1) * 32, &Bs[nxt][ldsSlot0]);
            load_lds16(bG1 + (kt + 1) * 32, &Bs[nxt][ldsSlot1]);
        }

        // compute on buf[cur]
        #pragma unroll
        for (int h = 0; h < 2; ++h) {
            const int c = h * 2 + half;
            bf16x8 af[4], bfr[2];
            #pragma unroll
            for (int mi = 0; mi < 4; ++mi)
                af[mi] = As[cur][c * 256 + wm * 128 + mi * 32 + l32];
            #pragma unroll
            for (int nj = 0; nj < 2; ++nj)
                bfr[nj] = Bs[cur][c * 128 + wn * 64 + nj * 32 + l32];
            #pragma unroll
            for (int mi = 0; mi < 4; ++mi)
                #pragma unroll
                for (int nj = 0; nj < 2; ++nj)
                    acc[mi][nj] = __builtin_amdgcn_mfma_f32_32x32x16_bf16(
                        af[mi], bfr[nj], acc[mi][nj], 0, 0, 0);
        }
    }

    // ---- epilogue: partial logits
    // C/D layout 32x32: col = l32, row = (reg&3) + 8*(reg>>2) + 4*half
    const int b     = by >> 3;
    const int sbase = (by & 7) * 256 + wm * 128;
    float ew[2], wv[2];
    #pragma unroll
    for (int nj = 0; nj < 2; ++nj) {
        int c = bx * 128 + wn * 64 + nj * 32 + l32;
        ew[nj] = embh[b * DM_ + c];
        wv[nj] = w2[c];
    }
    float* plw = plog + (size_t)(bx * 2 + wn) * MTOT + b * S_;
    #pragma unroll
    for (int mi = 0; mi < 4; ++mi) {
        #pragma unroll
        for (int reg = 0; reg < 16; ++reg) {
            float p = tanh_fast(acc[mi][0][reg] + ew[0]) * wv[0]
                    + tanh_fast(acc[mi][1][reg] + ew[1]) * wv[1];
            p += __shfl_xor(p, 1);
            p += __shfl_xor(p, 2);
            p += __shfl_xor(p, 4);
            p += __shfl_xor(p, 8);
            p += __shfl_xor(p, 16);
            if (l32 == 0) {
                int row = mi * 32 + (reg & 3) + 8 * (reg >> 2) + 4 * half;
                plw[sbase + row] = p;
            }
        }
    }
}

// ---------------------------------------------------------------------------
// Kernel 3: combine 8 partials, softmax over S per batch row
// ---------------------------------------------------------------------------
__global__ __launch_bounds__(256) void k_softmax(
    const float* __restrict__ plog, float* __restrict__ probs_out)
{
    int b = blockIdx.x;
    int t = threadIdx.x;
    float l[8];
    #pragma unroll
    for (int i = 0; i < 8; ++i) {
        int s = t + i * 256;
        float sum = 0.0f;
        #pragma unroll
        for (int p = 0; p < 8; ++p)
            sum += plog[(size_t)p * MTOT + b * S_ + s];
        l[i] = sum;
    }
    float mx = l[0];
    #pragma unroll
    for (int i = 1; i < 8; ++i) mx = fmaxf(mx, l[i]);
    #pragma unroll
    for (int off = 1; off < 64; off <<= 1) mx = fmaxf(mx, __shfl_xor(mx, off));
    __shared__ float redm[4];
    __shared__ float reds[4];
    int wid = t >> 6;
    if ((t & 63) == 0) redm[wid] = mx;
    __syncthreads();
    mx = fmaxf(fmaxf(redm[0], redm[1]), fmaxf(redm[2], redm[3]));

    float e[8];
    float es = 0.0f;
    #pragma unroll
    for (int i = 0; i < 8; ++i) {
        e[i] = __expf(l[i] - mx);
        es += e[i];
    }
    #pragma unroll
    for (int off = 1; off < 64; off <<= 1) es += __shfl_xor(es, off);
    if ((t & 63) == 0) reds[wid] = es;
    __syncthreads();
    es = reds[0] + reds[1] + reds[2] + reds[3];
    float inv = 1.0f / es;
    #pragma unroll
    for (int i = 0; i < 8; ++i)
        probs_out[b * S_ + t + i * 256] = e[i] * inv;
}

// ---------------------------------------------------------------------------
// Kernel 4a: partial context over 256-row s-chunks (deterministic, no atomics)
//   ctxp[z][b][d] = sum_{s in chunk z} probs[b][s] * feats[b][s][d]
// ---------------------------------------------------------------------------
__global__ __launch_bounds__(256) void k_context(
    const float* __restrict__ feats, const float* __restrict__ probs,
    float* __restrict__ ctxp)
{
    int d  = blockIdx.x * 256 + threadIdx.x;
    int b  = blockIdx.y;
    int z  = blockIdx.z;
    int s0 = z * 256;
    const float* f  = feats + ((size_t)b * S_ + s0) * DF_ + d;
    const float* pr = probs + b * S_ + s0;
    float acc = 0.0f;
    #pragma unroll 4
    for (int i = 0; i < 256; ++i)
        acc += pr[i] * f[(size_t)i * DF_];
    ctxp[((size_t)z * B_ + b) * DF_ + d] = acc;
}

// Kernel 4b: reduce the 8 chunk partials into the output
__global__ __launch_bounds__(256) void k_ctx_red(
    const float* __restrict__ ctxp, float* __restrict__ ctx)
{
    int i = blockIdx.x * 256 + threadIdx.x;
    float s = 0.0f;
    #pragma unroll
    for (int z = 0; z < 8; ++z)
        s += ctxp[(size_t)z * B_ * DF_ + i];
    ctx[i] = s;
}

// ---------------------------------------------------------------------------
extern "C" void kernel_launch(void* const* d_in, const int* in_sizes, int n_in,
                              void* d_out, int out_size, void* d_ws, size_t ws_size,
                              hipStream_t stream)
{
    const float* hidden = (const float*)d_in[0];
    const float* feats  = (const float*)d_in[1];
    const float* W1h    = (const float*)d_in[2];
    const float* b1h    = (const float*)d_in[3];
    const float* W1f    = (const float*)d_in[4];
    const float* b1f    = (const float*)d_in[5];
    const float* w2     = (const float*)d_in[6];

    float* out   = (float*)d_out;
    float* ctx   = out;              // [B, DF]   (output 0)
    float* probs = out + B_ * DF_;   // [B, 1, S] (output 1)

    char* ws = (char*)d_ws;
    float*          embh = (float*)ws;                                   // 64 KB
    unsigned short* w1fb = (unsigned short*)(ws + (64 << 10));           // 1 MB
    float*          plog = (float*)(ws + (64 << 10) + (1 << 20));        // 2 MB
    float*          ctxp = (float*)(ws + (64 << 10) + (3 << 20));        // 1 MB

    k_embh<<<dim3(B_, DM_ / 64), 256, 0, stream>>>(hidden, W1h, b1h, b1f, embh);
    k_cvt_w1f<<<dim3((DM_ * DF_ / 4) / 256), 256, 0, stream>>>(W1f, w1fb);
    k_gemm_logits<<<dim3((MTOT / 256) * (DM_ / 128)), 256, 0, stream>>>(
        feats, w1fb, embh, w2, plog);
    k_softmax<<<dim3(B_), 256, 0, stream>>>(plog, probs);
    k_context<<<dim3(DF_ / 256, B_, 8), 256, 0, stream>>>(feats, probs, ctxp);
    k_ctx_red<<<dim3(B_ * DF_ / 256), 256, 0, stream>>>(ctxp, ctx);
}

// Round 3
// 574.719 us; speedup vs baseline: 1.0435x; 1.0230x over previous
//
#include <hip/hip_runtime.h>
#include <hip/hip_bf16.h>
#include <cstdint>
#include <cstddef>

#define B_   32
#define S_   2048
#define DH_  1024
#define DF_  1024
#define DM_  512
#define MTOT (B_ * S_)   // 65536

typedef __attribute__((ext_vector_type(8))) short bf16x8;
typedef __attribute__((ext_vector_type(4))) float f32x4;

#define AS1 __attribute__((address_space(1)))
#define AS3 __attribute__((address_space(3)))

static __device__ __forceinline__ void load_lds16(const void* g, void* l) {
    __builtin_amdgcn_global_load_lds((const AS1 unsigned*)g, (AS3 unsigned*)l,
                                     16, 0, 0);
}

// fp32 pair -> packed bf16, round-half-up (cheap)
static __device__ __forceinline__ unsigned pack_rhu(float a, float b) {
    unsigned ua = (__float_as_uint(a) + 0x8000u) >> 16;
    unsigned ub = (__float_as_uint(b) + 0x8000u) & 0xFFFF0000u;
    return ua | ub;
}

static __device__ __forceinline__ float tanh_fast(float x) {
    float e = __expf(2.0f * x);
    return 1.0f - 2.0f / (e + 1.0f);
}

// ---------------------------------------------------------------------------
// embh[b][m] = dot(hidden[b], W1h[m]) + b1h[m] + b1f[m]
// ---------------------------------------------------------------------------
__global__ __launch_bounds__(256) void k_embh(
    const float* __restrict__ hidden, const float* __restrict__ W1h,
    const float* __restrict__ b1h, const float* __restrict__ b1f,
    float* __restrict__ embh)
{
    int b  = blockIdx.x;
    int mg = blockIdx.y;
    int t  = threadIdx.x;
    int m  = mg * 64 + (t >> 2);
    int kp = (t & 3) * 256;
    const float4* h4 = (const float4*)(hidden + (size_t)b * DH_ + kp);
    const float4* w4 = (const float4*)(W1h + (size_t)m * DH_ + kp);
    float s = 0.0f;
    #pragma unroll 8
    for (int i = 0; i < 64; ++i) {
        float4 a = h4[i];
        float4 w = w4[i];
        s += a.x * w.x + a.y * w.y + a.z * w.z + a.w * w.w;
    }
    s += __shfl_xor(s, 1);
    s += __shfl_xor(s, 2);
    if ((t & 3) == 0)
        embh[b * DM_ + m] = s + b1h[m] + b1f[m];
}

// ---------------------------------------------------------------------------
// fp32 -> bf16 streaming convert (used for W1f and, in main path, feats)
// 8 elements per thread
// ---------------------------------------------------------------------------
__global__ __launch_bounds__(256) void k_cvt(
    const float* __restrict__ src, unsigned short* __restrict__ dst)
{
    size_t i = (size_t)blockIdx.x * 256 + threadIdx.x;
    float4 a = ((const float4*)src)[2 * i];
    float4 b = ((const float4*)src)[2 * i + 1];
    uint4 r;
    r.x = pack_rhu(a.x, a.y);
    r.y = pack_rhu(a.z, a.w);
    r.z = pack_rhu(b.x, b.y);
    r.w = pack_rhu(b.z, b.w);
    ((uint4*)dst)[i] = r;
}

// ---------------------------------------------------------------------------
// MAIN GEMM (bf16 A from pre-converted feats): m97 structure.
//   128(M) x 128(N) x BK=32, mfma_f32_16x16x32_bf16, 4 waves as 2x2 (64x64).
//   LDS single-buffered 2 x 8 KB, chunk-of-8 layout [c][row], 16B slots.
//   ALL staging via global_load_lds width 16 (no VALU repack).
//   Grid 1D 2048 swizzled: 4 bx-sharers of an A-tile are == mod 8 -> same XCD.
//   Epilogue: tanh(acc+embh)*w2, 16-lane reduce -> plog[bx*2+wn][B][S]
// ---------------------------------------------------------------------------
__global__ __launch_bounds__(256) void k_gemm_bf(
    const unsigned short* __restrict__ fb, const unsigned short* __restrict__ wb,
    const float* __restrict__ embh, const float* __restrict__ w2,
    float* __restrict__ plog)
{
    __shared__ bf16x8 As[4 * 128];   // 8 KB
    __shared__ bf16x8 Bs[4 * 128];   // 8 KB

    const int t    = threadIdx.x;
    const int lane = t & 63;
    const int w    = t >> 6;
    const int wm   = w >> 1;
    const int wn   = w & 1;
    const int quad = lane >> 4;
    const int l16  = lane & 15;

    const int blk   = blockIdx.x;
    const int panel = blk >> 5;
    const int sub   = blk & 31;
    const int bx    = sub >> 3;                // 0..3   N tile
    const int by    = panel * 8 + (sub & 7);   // 0..511 M tile

    // staging: wave w covers k-chunk c=w; 2 instrs cover rows 0..63 / 64..127
    const unsigned short* aG0 = fb + ((size_t)(by * 128) + lane) * DF_ + w * 8;
    const unsigned short* aG1 = aG0 + (size_t)64 * DF_;
    const unsigned short* bG0 = wb + ((size_t)(bx * 128) + lane) * DF_ + w * 8;
    const unsigned short* bG1 = bG0 + (size_t)64 * DF_;
    bf16x8* ldsA0 = &As[w * 128];
    bf16x8* ldsA1 = &As[w * 128 + 64];
    bf16x8* ldsB0 = &Bs[w * 128];
    bf16x8* ldsB1 = &Bs[w * 128 + 64];

    f32x4 acc[4][4];
    const f32x4 zero = {0.0f, 0.0f, 0.0f, 0.0f};
    #pragma unroll
    for (int i = 0; i < 4; ++i)
        #pragma unroll
        for (int j = 0; j < 4; ++j) acc[i][j] = zero;

    for (int kt = 0; kt < DF_ / 32; ++kt) {
        __syncthreads();   // previous iter's LDS readers done
        load_lds16(aG0 + kt * 32, ldsA0);
        load_lds16(aG1 + kt * 32, ldsA1);
        load_lds16(bG0 + kt * 32, ldsB0);
        load_lds16(bG1 + kt * 32, ldsB1);
        __syncthreads();   // vmcnt drained -> tiles ready

        bf16x8 af[4], bfr[4];
        #pragma unroll
        for (int mi = 0; mi < 4; ++mi)
            af[mi] = As[quad * 128 + wm * 64 + mi * 16 + l16];
        #pragma unroll
        for (int nj = 0; nj < 4; ++nj)
            bfr[nj] = Bs[quad * 128 + wn * 64 + nj * 16 + l16];

        #pragma unroll
        for (int mi = 0; mi < 4; ++mi)
            #pragma unroll
            for (int nj = 0; nj < 4; ++nj)
                acc[mi][nj] = __builtin_amdgcn_mfma_f32_16x16x32_bf16(
                    af[mi], bfr[nj], acc[mi][nj], 0, 0, 0);
    }

    // epilogue (validated in R1): C/D 16x16 layout col=l16, row=quad*4+reg
    const int bIdx = by >> 4;
    float ew[4], wv[4];
    #pragma unroll
    for (int nj = 0; nj < 4; ++nj) {
        int c = bx * 128 + wn * 64 + nj * 16 + l16;
        ew[nj] = embh[bIdx * DM_ + c];
        wv[nj] = w2[c];
    }
    float* plw = plog + (size_t)(bx * 2 + wn) * MTOT + bIdx * S_;
    #pragma unroll
    for (int mi = 0; mi < 4; ++mi) {
        #pragma unroll
        for (int reg = 0; reg < 4; ++reg) {
            float p = 0.0f;
            #pragma unroll
            for (int nj = 0; nj < 4; ++nj)
                p += tanh_fast(acc[mi][nj][reg] + ew[nj]) * wv[nj];
            p += __shfl_xor(p, 1);
            p += __shfl_xor(p, 2);
            p += __shfl_xor(p, 4);
            p += __shfl_xor(p, 8);
            if (l16 == 0) {
                int rowl = wm * 64 + mi * 16 + quad * 4 + reg;
                int s = (by * 128 + rowl) & (S_ - 1);
                plw[s] = p;
            }
        }
    }
}

// ---------------------------------------------------------------------------
// FALLBACK GEMM (fp32 A, in-kernel cheap pack) — R1 structure, used only if
// ws is too small for the bf16 feats copy.
// ---------------------------------------------------------------------------
__global__ __launch_bounds__(256) void k_gemm_f32(
    const float* __restrict__ feats, const unsigned short* __restrict__ w1fb,
    const float* __restrict__ embh, const float* __restrict__ w2,
    float* __restrict__ plog)
{
    __shared__ bf16x8 As[4 * 128];
    __shared__ bf16x8 Bs[4 * 128];

    const int t    = threadIdx.x;
    const int lane = t & 63;
    const int w    = t >> 6;
    const int wm   = w >> 1;
    const int wn   = w & 1;
    const int quad = lane >> 4;
    const int l16  = lane & 15;
    const int blk   = blockIdx.x;
    const int panel = blk >> 5;
    const int sub   = blk & 31;
    const int bx    = sub >> 3;
    const int by    = panel * 8 + (sub & 7);

    const int sRow = t >> 1;
    const int sK   = (t & 1) * 16;
    const int c0   = sK >> 3;
    const float*          aG = feats + (size_t)(by * 128 + sRow) * DF_ + sK;
    const unsigned short* bG = w1fb  + (size_t)(bx * 128 + sRow) * DF_ + sK;

    f32x4 acc[4][4];
    const f32x4 zero = {0.0f, 0.0f, 0.0f, 0.0f};
    #pragma unroll
    for (int i = 0; i < 4; ++i)
        #pragma unroll
        for (int j = 0; j < 4; ++j) acc[i][j] = zero;

    for (int kt = 0; kt < DF_ / 32; ++kt) {
        float4 a0 = *(const float4*)(aG + kt * 32);
        float4 a1 = *(const float4*)(aG + kt * 32 + 4);
        float4 a2 = *(const float4*)(aG + kt * 32 + 8);
        float4 a3 = *(const float4*)(aG + kt * 32 + 12);
        uint4  b0 = *(const uint4*)(bG + kt * 32);
        uint4  b1 = *(const uint4*)(bG + kt * 32 + 8);

        __syncthreads();

        union { unsigned u[4]; bf16x8 v; } pa;
        pa.u[0] = pack_rhu(a0.x, a0.y);
        pa.u[1] = pack_rhu(a0.z, a0.w);
        pa.u[2] = pack_rhu(a1.x, a1.y);
        pa.u[3] = pack_rhu(a1.z, a1.w);
        As[c0 * 128 + sRow] = pa.v;
        pa.u[0] = pack_rhu(a2.x, a2.y);
        pa.u[1] = pack_rhu(a2.z, a2.w);
        pa.u[2] = pack_rhu(a3.x, a3.y);
        pa.u[3] = pack_rhu(a3.z, a3.w);
        As[(c0 + 1) * 128 + sRow] = pa.v;

        union { uint4 q; bf16x8 v; } pb;
        pb.q = b0;
        Bs[c0 * 128 + sRow] = pb.v;
        pb.q = b1;
        Bs[(c0 + 1) * 128 + sRow] = pb.v;

        __syncthreads();

        bf16x8 af[4], bfr[4];
        #pragma unroll
        for (int mi = 0; mi < 4; ++mi)
            af[mi] = As[quad * 128 + wm * 64 + mi * 16 + l16];
        #pragma unroll
        for (int nj = 0; nj < 4; ++nj)
            bfr[nj] = Bs[quad * 128 + wn * 64 + nj * 16 + l16];

        #pragma unroll
        for (int mi = 0; mi < 4; ++mi)
            #pragma unroll
            for (int nj = 0; nj < 4; ++nj)
                acc[mi][nj] = __builtin_amdgcn_mfma_f32_16x16x32_bf16(
                    af[mi], bfr[nj], acc[mi][nj], 0, 0, 0);
    }

    const int bIdx = by >> 4;
    float ew[4], wv[4];
    #pragma unroll
    for (int nj = 0; nj < 4; ++nj) {
        int c = bx * 128 + wn * 64 + nj * 16 + l16;
        ew[nj] = embh[bIdx * DM_ + c];
        wv[nj] = w2[c];
    }
    float* plw = plog + (size_t)(bx * 2 + wn) * MTOT + bIdx * S_;
    #pragma unroll
    for (int mi = 0; mi < 4; ++mi) {
        #pragma unroll
        for (int reg = 0; reg < 4; ++reg) {
            float p = 0.0f;
            #pragma unroll
            for (int nj = 0; nj < 4; ++nj)
                p += tanh_fast(acc[mi][nj][reg] + ew[nj]) * wv[nj];
            p += __shfl_xor(p, 1);
            p += __shfl_xor(p, 2);
            p += __shfl_xor(p, 4);
            p += __shfl_xor(p, 8);
            if (l16 == 0) {
                int rowl = wm * 64 + mi * 16 + quad * 4 + reg;
                int s = (by * 128 + rowl) & (S_ - 1);
                plw[s] = p;
            }
        }
    }
}

// ---------------------------------------------------------------------------
// combine 8 partials, softmax over S per batch row
// ---------------------------------------------------------------------------
__global__ __launch_bounds__(256) void k_softmax(
    const float* __restrict__ plog, float* __restrict__ probs_out)
{
    int b = blockIdx.x;
    int t = threadIdx.x;
    float l[8];
    #pragma unroll
    for (int i = 0; i < 8; ++i) {
        int s = t + i * 256;
        float sum = 0.0f;
        #pragma unroll
        for (int p = 0; p < 8; ++p)
            sum += plog[(size_t)p * MTOT + b * S_ + s];
        l[i] = sum;
    }
    float mx = l[0];
    #pragma unroll
    for (int i = 1; i < 8; ++i) mx = fmaxf(mx, l[i]);
    #pragma unroll
    for (int off = 1; off < 64; off <<= 1) mx = fmaxf(mx, __shfl_xor(mx, off));
    __shared__ float redm[4];
    __shared__ float reds[4];
    int wid = t >> 6;
    if ((t & 63) == 0) redm[wid] = mx;
    __syncthreads();
    mx = fmaxf(fmaxf(redm[0], redm[1]), fmaxf(redm[2], redm[3]));

    float e[8];
    float es = 0.0f;
    #pragma unroll
    for (int i = 0; i < 8; ++i) {
        e[i] = __expf(l[i] - mx);
        es += e[i];
    }
    #pragma unroll
    for (int off = 1; off < 64; off <<= 1) es += __shfl_xor(es, off);
    if ((t & 63) == 0) reds[wid] = es;
    __syncthreads();
    es = reds[0] + reds[1] + reds[2] + reds[3];
    float inv = 1.0f / es;
    #pragma unroll
    for (int i = 0; i < 8; ++i)
        probs_out[b * S_ + t + i * 256] = e[i] * inv;
}

// ---------------------------------------------------------------------------
// context partials (bf16 feats). Each thread: 2 adjacent d via dword loads.
//   ctxp[z][b][d] = sum_{s in chunk z} probs[b][s] * feats[b][s][d]
// ---------------------------------------------------------------------------
__global__ __launch_bounds__(256) void k_context_bf(
    const unsigned short* __restrict__ fb, const float* __restrict__ probs,
    float* __restrict__ ctxp)
{
    int dp = blockIdx.x * 256 + threadIdx.x;   // d-pair
    int b  = blockIdx.y;
    int z  = blockIdx.z;
    const unsigned* f  = (const unsigned*)(fb + ((size_t)b * S_ + z * 256) * DF_) + dp;
    const float*    pr = probs + b * S_ + z * 256;
    float a0 = 0.0f, a1 = 0.0f;
    #pragma unroll 4
    for (int i = 0; i < 256; ++i) {
        unsigned v = f[(size_t)i * (DF_ / 2)];
        float lo = __uint_as_float(v << 16);
        float hi = __uint_as_float(v & 0xFFFF0000u);
        float p = pr[i];
        a0 += p * lo;
        a1 += p * hi;
    }
    float2* o = (float2*)(ctxp + ((size_t)z * B_ + b) * DF_) + dp;
    *o = make_float2(a0, a1);
}

// fp32-feats fallback context
__global__ __launch_bounds__(256) void k_context_f32(
    const float* __restrict__ feats, const float* __restrict__ probs,
    float* __restrict__ ctxp)
{
    int d  = blockIdx.x * 256 + threadIdx.x;
    int b  = blockIdx.y;
    int z  = blockIdx.z;
    const float* f  = feats + ((size_t)b * S_ + z * 256) * DF_ + d;
    const float* pr = probs + b * S_ + z * 256;
    float acc = 0.0f;
    #pragma unroll 4
    for (int i = 0; i < 256; ++i)
        acc += pr[i] * f[(size_t)i * DF_];
    ctxp[((size_t)z * B_ + b) * DF_ + d] = acc;
}

__global__ __launch_bounds__(256) void k_ctx_red(
    const float* __restrict__ ctxp, float* __restrict__ ctx)
{
    int i = blockIdx.x * 256 + threadIdx.x;
    float s = 0.0f;
    #pragma unroll
    for (int z = 0; z < 8; ++z)
        s += ctxp[(size_t)z * B_ * DF_ + i];
    ctx[i] = s;
}

// ---------------------------------------------------------------------------
extern "C" void kernel_launch(void* const* d_in, const int* in_sizes, int n_in,
                              void* d_out, int out_size, void* d_ws, size_t ws_size,
                              hipStream_t stream)
{
    const float* hidden = (const float*)d_in[0];
    const float* feats  = (const float*)d_in[1];
    const float* W1h    = (const float*)d_in[2];
    const float* b1h    = (const float*)d_in[3];
    const float* W1f    = (const float*)d_in[4];
    const float* b1f    = (const float*)d_in[5];
    const float* w2     = (const float*)d_in[6];

    float* out   = (float*)d_out;
    float* ctx   = out;              // [B, DF]   (output 0)
    float* probs = out + B_ * DF_;   // [B, 1, S] (output 1)

    char* ws = (char*)d_ws;
    float*          embh  = (float*)ws;                              // 64 KB
    unsigned short* w1fb  = (unsigned short*)(ws + (64 << 10));      // 1 MB
    float*          plog  = (float*)(ws + (64 << 10) + (1 << 20));   // 2 MB
    float*          ctxp  = (float*)(ws + (64 << 10) + (3 << 20));   // 1 MB
    unsigned short* featb = (unsigned short*)(ws + (8 << 20));       // 128 MB

    const bool big_ws = ws_size >= ((size_t)8 << 20) + ((size_t)B_ * S_ * DF_ * 2);

    k_embh<<<dim3(B_, DM_ / 64), 256, 0, stream>>>(hidden, W1h, b1h, b1f, embh);
    k_cvt<<<dim3((DM_ * DF_ / 8) / 256), 256, 0, stream>>>(W1f, w1fb);

    if (big_ws) {
        k_cvt<<<dim3(((size_t)MTOT * DF_ / 8) / 256), 256, 0, stream>>>(feats, featb);
        k_gemm_bf<<<dim3((MTOT / 128) * (DM_ / 128)), 256, 0, stream>>>(
            featb, w1fb, embh, w2, plog);
        k_softmax<<<dim3(B_), 256, 0, stream>>>(plog, probs);
        k_context_bf<<<dim3(DF_ / 512, B_, 8), 256, 0, stream>>>(featb, probs, ctxp);
    } else {
        k_gemm_f32<<<dim3((MTOT / 128) * (DM_ / 128)), 256, 0, stream>>>(
            feats, w1fb, embh, w2, plog);
        k_softmax<<<dim3(B_), 256, 0, stream>>>(plog, probs);
        k_context_f32<<<dim3(DF_ / 256, B_, 8), 256, 0, stream>>>(feats, probs, ctxp);
    }
    k_ctx_red<<<dim3(B_ * DF_ / 256), 256, 0, stream>>>(ctxp, ctx);
}